// Round 1
// baseline (749.497 us; speedup 1.0000x reference)
//
#include <hip/hip_runtime.h>

// Problem constants (from reference)
constexpr int B       = 64;
constexpr int F       = 4096;   // FOLD
constexpr int K       = 32;     // KERNEL
constexpr int O       = 512;    // OUT_CH
constexpr int STRIDE  = 16;
constexpr int PAD     = 8;
constexpr int IN_LEN  = 65536;

// Tiling
constexpr int O_TILE  = 256;    // o-columns per block
constexpr int BLOCK   = 256;    // threads per block

// out[b,f,o] = sum_k xp[b, f*16 + k] * w[f,k,o],  xp = x zero-padded by 8
__global__ __launch_bounds__(BLOCK)
void Local_39152921870765_kernel(const float* __restrict__ x,
                                 const float* __restrict__ w,
                                 float* __restrict__ out)
{
    const int f   = blockIdx.y;
    const int o0  = blockIdx.x * O_TILE;
    const int tid = threadIdx.x;

    __shared__ float w_s[K][O_TILE];  // 32 KB
    __shared__ float x_s[K][B];       // 8 KB, [k][b] so b is contiguous

    // ---- stage weight tile (coalesced float4) ----
    {
        const float4* wg  = (const float4*)(w + (size_t)f * K * O + o0);
        float4*       ws4 = (float4*)(&w_s[0][0]);
        #pragma unroll
        for (int j = tid; j < (K * O_TILE) / 4; j += BLOCK) {
            const int k  = j >> 6;        // O_TILE/4 = 64 float4 per row
            const int o4 = j & 63;
            ws4[j] = wg[k * (O / 4) + o4];
        }
    }

    // ---- stage x window with zero padding: x_s[k][b] = xp[b, f*16+k] ----
    {
        const int b    = tid >> 2;        // 0..63
        const int kq   = (tid & 3) * 8;   // 8 consecutive k per thread (coalesced-ish)
        const int base = f * STRIDE - PAD;
        #pragma unroll
        for (int i = 0; i < 8; ++i) {
            const int k  = kq + i;
            const int gi = base + k;
            float v = 0.0f;
            if (gi >= 0 && gi < IN_LEN) v = x[(size_t)b * IN_LEN + gi];
            x_s[k][b] = v;
        }
    }
    __syncthreads();

    // ---- per-thread 8b x 8o register tile ----
    const int og = tid & 31;     // lane-contiguous o within half-wave
    const int bg = tid >> 5;     // 0..7
    const int ob = og * 4;       // float4 #1 at ob, #2 at ob+128
    const int bb = bg * 8;       // 8 consecutive batches

    float acc[8][8];
    #pragma unroll
    for (int i = 0; i < 8; ++i)
        #pragma unroll
        for (int j = 0; j < 8; ++j) acc[i][j] = 0.0f;

    #pragma unroll 4
    for (int k = 0; k < K; ++k) {
        const float4 w0 = *(const float4*)&w_s[k][ob];
        const float4 w1 = *(const float4*)&w_s[k][ob + 128];
        const float4 xa = *(const float4*)&x_s[k][bb];
        const float4 xb = *(const float4*)&x_s[k][bb + 4];
        const float xv[8] = {xa.x, xa.y, xa.z, xa.w, xb.x, xb.y, xb.z, xb.w};
        const float wv[8] = {w0.x, w0.y, w0.z, w0.w, w1.x, w1.y, w1.z, w1.w};
        #pragma unroll
        for (int i = 0; i < 8; ++i)
            #pragma unroll
            for (int j = 0; j < 8; ++j)
                acc[i][j] = fmaf(xv[i], wv[j], acc[i][j]);
    }

    // ---- write out[b][f][o]: two float4 per batch row, lane-contiguous ----
    #pragma unroll
    for (int i = 0; i < 8; ++i) {
        const size_t base = ((size_t)(bb + i) * F + f) * O + o0;
        const float4 v0 = make_float4(acc[i][0], acc[i][1], acc[i][2], acc[i][3]);
        const float4 v1 = make_float4(acc[i][4], acc[i][5], acc[i][6], acc[i][7]);
        *(float4*)(out + base + ob)       = v0;
        *(float4*)(out + base + ob + 128) = v1;
    }
}

extern "C" void kernel_launch(void* const* d_in, const int* in_sizes, int n_in,
                              void* d_out, int out_size, void* d_ws, size_t ws_size,
                              hipStream_t stream) {
    const float* x = (const float*)d_in[0];   // (64, 65536) fp32
    const float* w = (const float*)d_in[1];   // (4096, 32, 512) fp32
    float* out = (float*)d_out;               // (64, 4096, 512) fp32

    dim3 grid(O / O_TILE, F);                 // (2, 4096)
    Local_39152921870765_kernel<<<grid, BLOCK, 0, stream>>>(x, w, out);
}